// Round 10
// baseline (188.560 us; speedup 1.0000x reference)
//
#include <hip/hip_runtime.h>
#include <hip/hip_bf16.h>
#include <cstdint>
#include <cstddef>

#define BB 4
#define SEQ 2048
#define CD 768
#define NH 12
#define DH 64
#define MROWS (BB*SEQ)      // 8192
#define NQKV (3*CD)         // 2304

typedef float f32x4 __attribute__((ext_vector_type(4)));
typedef float f32x16 __attribute__((ext_vector_type(16)));
typedef short bf16x8 __attribute__((ext_vector_type(8)));

static __device__ __forceinline__ unsigned short f2bf(float f) {
  union { float f; unsigned int u; } cv; cv.f = f;
  unsigned int u = cv.u;
  unsigned int r = (u + 0x7FFFu + ((u >> 16) & 1u)) >> 16;
  return (unsigned short)r;
}

// raw v_exp_f32: our exponents are bounded (|x| <= ~23), no OCML fixups needed
static __device__ __forceinline__ float fexp2(float x) {
#if __has_builtin(__builtin_amdgcn_exp2f)
  return __builtin_amdgcn_exp2f(x);
#else
  float r; asm("v_exp_f32 %0, %1" : "=v"(r) : "v"(x)); return r;
#endif
}

#define GAS __attribute__((address_space(1)))
#define LAS __attribute__((address_space(3)))
static __device__ __forceinline__ void gl2lds16(const void* g, void* l) {
  __builtin_amdgcn_global_load_lds((const GAS void*)g, (LAS void*)l, 16, 0, 0);
}

#define MFMA(a, b, c) __builtin_amdgcn_mfma_f32_16x16x32_bf16((a), (b), (c), 0, 0, 0)
#define MFMA32(a, b, c) __builtin_amdgcn_mfma_f32_32x32x16_bf16((a), (b), (c), 0, 0, 0)
#define PACKBF(dst, x, y) asm("v_cvt_pk_bf16_f32 %0, %1, %2" : "=v"(dst) : "v"(x), "v"(y))
#define SWAP32(a, b) asm("v_permlane32_swap_b32 %0, %1" : "+v"(a), "+v"(b))

// 0.125 (1/sqrt(Dh)) * log2(e): folded into Q's gamma/beta so softmax uses exp2 directly.
// With LN'd q,k scores are bounded (|log2 score| <= 11.5) -> no max subtraction needed.
#define QSC 0.18033688011112042f

// ---------------- fp32 -> bf16 convert ----------------
__global__ __launch_bounds__(256) void cvt_bf16(const float* __restrict__ in,
                                                unsigned short* __restrict__ out, int n4) {
  int i = blockIdx.x * 256 + threadIdx.x;
  if (i >= n4) return;
  float4 v = reinterpret_cast<const float4*>(in)[i];
  unsigned int lo = (unsigned int)f2bf(v.x) | ((unsigned int)f2bf(v.y) << 16);
  unsigned int hi = (unsigned int)f2bf(v.z) | ((unsigned int)f2bf(v.w) << 16);
  reinterpret_cast<uint2*>(out)[i] = make_uint2(lo, hi);
}

// ---------------- QKV GEMM: 128x128 tile, BK=64, 4 waves, swizzled LDS ----------------
__global__ __launch_bounds__(256) void qkv_gemm(
    const unsigned short* __restrict__ Xb, const unsigned short* __restrict__ Wb,
    const float* __restrict__ bias,
    const float* __restrict__ qg, const float* __restrict__ qbt,
    const float* __restrict__ kg, const float* __restrict__ kbt,
    unsigned short* __restrict__ Qo, unsigned short* __restrict__ Ko,
    unsigned short* __restrict__ Vt) {
  __shared__ unsigned short Als[2][128 * 64];   // 32KB
  __shared__ unsigned short Bls[2][128 * 64];   // 32KB
  const int tid = threadIdx.x;
  const int wid = tid >> 6, lane = tid & 63;
  const int g = lane >> 4, cl = lane & 15;
  const int wr = (wid >> 1) * 64, wc = (wid & 1) * 64;

  // XCD-bijective swizzle: grid 1152 = 8 * 144; contiguous wgid share bm (A-panel L2 reuse)
  const int wg = blockIdx.x;
  const int wgid = (wg & 7) * 144 + (wg >> 3);
  const int bm = wgid / 18, bn = wgid % 18;

  f32x4 acc[4][4] = {};

  const int srow = tid >> 3;                      // 0..31
  const int scol = ((tid & 7) ^ (srow & 7)) * 8;  // pre-swizzled source col
  const unsigned short* Abase = Xb + (size_t)(bm * 128 + srow) * CD + scol;
  const unsigned short* Bbase = Wb + (size_t)(bn * 128 + srow) * CD + scol;

#define QSTG(buf, kt)                                                         \
  do {                                                                        \
    gl2lds16(Abase + (size_t)0 * 32 * CD + (kt) * 64, &Als[buf][0 * 2048 + tid * 8]); \
    gl2lds16(Abase + (size_t)1 * 32 * CD + (kt) * 64, &Als[buf][1 * 2048 + tid * 8]); \
    gl2lds16(Abase + (size_t)2 * 32 * CD + (kt) * 64, &Als[buf][2 * 2048 + tid * 8]); \
    gl2lds16(Abase + (size_t)3 * 32 * CD + (kt) * 64, &Als[buf][3 * 2048 + tid * 8]); \
    gl2lds16(Bbase + (size_t)0 * 32 * CD + (kt) * 64, &Bls[buf][0 * 2048 + tid * 8]); \
    gl2lds16(Bbase + (size_t)1 * 32 * CD + (kt) * 64, &Bls[buf][1 * 2048 + tid * 8]); \
    gl2lds16(Bbase + (size_t)2 * 32 * CD + (kt) * 64, &Bls[buf][2 * 2048 + tid * 8]); \
    gl2lds16(Bbase + (size_t)3 * 32 * CD + (kt) * 64, &Bls[buf][3 * 2048 + tid * 8]); \
  } while (0)

  QSTG(0, 0);
  __syncthreads();
  const int NKT = CD / 64;  // 12
  for (int kt = 0; kt < NKT; ++kt) {
    const int cur = kt & 1;
    if (kt + 1 < NKT) QSTG(cur ^ 1, kt + 1);
    bf16x8 bfr[4][2];
#pragma unroll
    for (int j = 0; j < 4; ++j) {
      const int Bcol = wc + j * 16 + cl;
      const int sw = (Bcol & 7) << 3;
      bfr[j][0] = *(const bf16x8*)&Bls[cur][Bcol * 64 + ((g * 8) ^ sw)];
      bfr[j][1] = *(const bf16x8*)&Bls[cur][Bcol * 64 + ((32 + g * 8) ^ sw)];
    }
    __builtin_amdgcn_s_setprio(1);
#pragma unroll
    for (int i = 0; i < 4; ++i) {
      const int Arow = wr + i * 16 + cl;
      const int sw = (Arow & 7) << 3;
      bf16x8 a0 = *(const bf16x8*)&Als[cur][Arow * 64 + ((g * 8) ^ sw)];
      bf16x8 a1 = *(const bf16x8*)&Als[cur][Arow * 64 + ((32 + g * 8) ^ sw)];
#pragma unroll
      for (int j = 0; j < 4; ++j) {
        acc[i][j] = MFMA(a0, bfr[j][0], acc[i][j]);
        acc[i][j] = MFMA(a1, bfr[j][1], acc[i][j]);
      }
    }
    __builtin_amdgcn_s_setprio(0);
    __syncthreads();
  }
#undef QSTG

  const int j0 = bn * 128 + wc;
  const int t = j0 / CD;
  const int h = (j0 % CD) / DH;
  float bia[4], gam[4] = {0, 0, 0, 0}, bet[4] = {0, 0, 0, 0};
#pragma unroll
  for (int j = 0; j < 4; ++j) {
    int d = j * 16 + cl;
    bia[j] = bias[j0 + d];
    if (t == 0) { gam[j] = qg[d] * QSC; bet[j] = qbt[d] * QSC; }
    else if (t == 1) { gam[j] = kg[d]; bet[j] = kbt[d]; }
  }

  if (t == 2) {
#pragma unroll
    for (int i = 0; i < 4; ++i) {
      const int mrow = bm * 128 + wr + i * 16 + g * 4;
      const int b = mrow >> 11, nn = mrow & 2047;
#pragma unroll
      for (int j = 0; j < 4; ++j) {
        const int d = j * 16 + cl;
        unsigned int lo = (unsigned int)f2bf(acc[i][j][0] + bia[j]) |
                          ((unsigned int)f2bf(acc[i][j][1] + bia[j]) << 16);
        unsigned int hi2 = (unsigned int)f2bf(acc[i][j][2] + bia[j]) |
                           ((unsigned int)f2bf(acc[i][j][3] + bia[j]) << 16);
        *reinterpret_cast<uint2*>(&Vt[((size_t)(b * NH + h) * DH + d) * SEQ + nn]) =
            make_uint2(lo, hi2);
      }
    }
    return;
  }

  unsigned short* Out = (t == 0) ? Qo : Ko;
#pragma unroll
  for (int i = 0; i < 4; ++i) {
#pragma unroll
    for (int r = 0; r < 4; ++r) {
      float vj[4];
#pragma unroll
      for (int j = 0; j < 4; ++j) vj[j] = acc[i][j][r] + bia[j];
      const int m = bm * 128 + wr + i * 16 + g * 4 + r;
      const int b = m >> 11, n = m & 2047;
      size_t base = ((size_t)(b * NH + h) * SEQ + n) * DH;
      float s = vj[0] + vj[1] + vj[2] + vj[3];
      float ss = vj[0] * vj[0] + vj[1] * vj[1] + vj[2] * vj[2] + vj[3] * vj[3];
#pragma unroll
      for (int msk = 1; msk < 16; msk <<= 1) {
        s += __shfl_xor(s, msk, 64);
        ss += __shfl_xor(ss, msk, 64);
      }
      float mu = s * (1.0f / 64.0f);
      float var = ss * (1.0f / 64.0f) - mu * mu;
      float rstd = rsqrtf(var + 1e-5f);
#pragma unroll
      for (int j = 0; j < 4; ++j)
        Out[base + j * 16 + cl] = f2bf((vj[j] - mu) * rstd * gam[j] + bet[j]);
    }
  }
}

// ---------------- Flash attention: swapped QK^T, K in LDS, V direct from L2 ----------------
// 4 waves x 32 q-rows (R8 structure). V^T fragments are loaded straight from global (per-head
// V = 256KB, L2-resident under the XCD swizzle; the 8KB tile is L1-shared across waves).
// V loads issue right after the barrier (before QK) and are consumed in PV: ~full-tile
// latency cover. K stays LDS-staged (consumed at tile start).
__global__ __launch_bounds__(256, 3) void attn_fwd(
    const unsigned short* __restrict__ Qb, const unsigned short* __restrict__ Kb,
    const unsigned short* __restrict__ Vtb, unsigned short* __restrict__ Ob) {
  __shared__ unsigned short kl[2][64 * 64];   // [key][d], 128B rows, XOR-swizzled (16KB)
  const int tid = threadIdx.x, wave = tid >> 6, lane = tid & 63;
  const int q32 = lane & 31, hi = lane >> 5;

  // XCD swizzle (T1): wg%8 = XCD; each XCD owns a contiguous chunk of (bh, qb) space
  const int wg = blockIdx.x;
  const int lin = (wg & 7) * 96 + (wg >> 3);   // 768 = 8 * 96, bijective
  const int bh = lin >> 4;
  const int qbase = (lin & 15) * 128 + wave * 32;

  const unsigned short* qrow = Qb + ((size_t)bh * SEQ + qbase + q32) * DH + hi * 8;
  bf16x8 qf[4];
#pragma unroll
  for (int dc = 0; dc < 4; ++dc) qf[dc] = *(const bf16x8*)&qrow[dc * 16];

  const unsigned short* Kh = Kb + (size_t)bh * SEQ * DH;
  const unsigned short* Vth = Vtb + (size_t)bh * DH * SEQ;
  // per-lane V^T row bases: lane reads d = q32 (vf0) and d = 32+q32 (vf1), col base hi*8
  const unsigned short* vb0 = Vth + (size_t)q32 * SEQ + hi * 8;
  const unsigned short* vb1 = Vth + (size_t)(32 + q32) * SEQ + hi * 8;

  const int sr = tid >> 3;
  const int sc = 8 * ((tid & 7) ^ (sr & 7));
  const int ksw = (q32 & 7) << 3;

  const short oneb = (short)0x3F80;  // bf16 1.0
  const bf16x8 onesv = {oneb, oneb, oneb, oneb, oneb, oneb, oneb, oneb};

#define ASTAGE(buf, kb0)                                                      \
  do {                                                                        \
    gl2lds16(&Kh[(size_t)((kb0) + sr) * DH + sc], &kl[buf][tid * 8]);         \
    gl2lds16(&Kh[(size_t)((kb0) + sr + 32) * DH + sc], &kl[buf][tid * 8 + 2048]); \
  } while (0)

  f32x16 o0 = {}, o1 = {}, ol = {};

  ASTAGE(0, 0);
  __syncthreads();
  const int NT = SEQ / 64;  // 32
#pragma unroll 2
  for (int it = 0; it < NT; ++it) {
    const int cur = it & 1;
    const int kb0 = it * 64;
    if (it + 1 < NT) ASTAGE(cur ^ 1, kb0 + 64);

    // issue V loads EARLY (consumed in PV at the end of the tile body)
    bf16x8 vfr[4][2];
#pragma unroll
    for (int c = 0; c < 4; ++c) {
      vfr[c][0] = *(const bf16x8*)&vb0[kb0 + c * 16];
      vfr[c][1] = *(const bf16x8*)&vb1[kb0 + c * 16];
    }

    // S^T = K . Q^T
    f32x16 s0 = {}, s1 = {};
    __builtin_amdgcn_s_setprio(1);
#pragma unroll
    for (int dc = 0; dc < 4; ++dc) {
      const int colb = dc * 16 + hi * 8;
      bf16x8 kf0 = *(const bf16x8*)&kl[cur][q32 * 64 + (colb ^ ksw)];
      bf16x8 kf1 = *(const bf16x8*)&kl[cur][(32 + q32) * 64 + (colb ^ ksw)];
      s0 = MFMA32(kf0, qf[dc], s0);
      s1 = MFMA32(kf1, qf[dc], s1);
    }
    __builtin_amdgcn_s_setprio(0);

    // P = exp2(S) directly (bounded scores, no max)
#pragma unroll
    for (int r = 0; r < 16; ++r) {
      s0[r] = fexp2(s0[r]);
      s1[r] = fexp2(s1[r]);
    }

    // P -> bf16 A-frags in-register
    bf16x8 pav[4];
#pragma unroll
    for (int c = 0; c < 4; ++c) {
      const int b = 8 * (c & 1);
      unsigned int wA0, wA1, wB0, wB1;
      if (c < 2) {
        PACKBF(wA0, s0[b + 0], s0[b + 1]); PACKBF(wA1, s0[b + 2], s0[b + 3]);
        PACKBF(wB0, s0[b + 4], s0[b + 5]); PACKBF(wB1, s0[b + 6], s0[b + 7]);
      } else {
        PACKBF(wA0, s1[b + 0], s1[b + 1]); PACKBF(wA1, s1[b + 2], s1[b + 3]);
        PACKBF(wB0, s1[b + 4], s1[b + 5]); PACKBF(wB1, s1[b + 6], s1[b + 7]);
      }
      SWAP32(wA0, wB0);
      SWAP32(wA1, wB1);
      union { unsigned int w[4]; bf16x8 v; } u;
      u.w[0] = wA0; u.w[1] = wA1; u.w[2] = wB0; u.w[3] = wB1;
      pav[c] = u.v;
    }

    // PV: O[q][d] += P[q][key] . V^T[d][key]; row-sum l via ones-MFMA
    __builtin_amdgcn_s_setprio(1);
#pragma unroll
    for (int c = 0; c < 4; ++c) {
      o0 = MFMA32(pav[c], vfr[c][0], o0);
      o1 = MFMA32(pav[c], vfr[c][1], o1);
      ol = MFMA32(pav[c], onesv, ol);
    }
    __builtin_amdgcn_s_setprio(0);
    __syncthreads();
  }
#undef ASTAGE

  const int b = bh / NH, h = bh % NH;
#pragma unroll
  for (int r = 0; r < 16; ++r) {
    const int qq = (r & 3) + 8 * (r >> 2) + 4 * hi;
    const float iv = __builtin_amdgcn_rcpf(ol[r]);
    size_t base = ((size_t)(b * SEQ + qbase + qq)) * CD + h * DH;
    Ob[base + q32] = f2bf(o0[r] * iv);
    Ob[base + 32 + q32] = f2bf(o1[r] * iv);
  }
}

// ---------------- Proj GEMM: 128x128 tile, BK=64, swizzled LDS, fp32 out ----------------
__global__ __launch_bounds__(256) void proj_gemm(
    const unsigned short* __restrict__ Ab, const unsigned short* __restrict__ Wb,
    const float* __restrict__ bias, float* __restrict__ out) {
  __shared__ unsigned short Als[2][128 * 64];   // 32KB
  __shared__ unsigned short Bls[2][128 * 64];   // 32KB
  const int tid = threadIdx.x;
  const int wid = tid >> 6, lane = tid & 63;
  const int g = lane >> 4, cl = lane & 15;
  const int bm = blockIdx.x, bn = blockIdx.y;
  const int wr = (wid >> 1) * 64, wc = (wid & 1) * 64;

  f32x4 acc[4][4] = {};

  const int srow = tid >> 3;                      // 0..31
  const int scol = ((tid & 7) ^ (srow & 7)) * 8;
  const unsigned short* Abase = Ab + (size_t)(bm * 128 + srow) * CD + scol;
  const unsigned short* Bbase = Wb + (size_t)(bn * 128 + srow) * CD + scol;

#define PSTG(buf, kt)                                                         \
  do {                                                                        \
    gl2lds16(Abase + (size_t)0 * 32 * CD + (kt) * 64, &Als[buf][0 * 2048 + tid * 8]); \
    gl2lds16(Abase + (size_t)1 * 32 * CD + (kt) * 64, &Als[buf][1 * 2048 + tid * 8]); \
    gl2lds16(Abase + (size_t)2 * 32 * CD + (kt) * 64, &Als[buf][2 * 2048 + tid * 8]); \
    gl2lds16(Abase + (size_t)3 * 32 * CD + (kt) * 64, &Als[buf][3 * 2048 + tid * 8]); \
    gl2lds16(Bbase + (size_t)0 * 32 * CD + (kt) * 64, &Bls[buf][0 * 2048 + tid * 8]); \
    gl2lds16(Bbase + (size_t)1 * 32 * CD + (kt) * 64, &Bls[buf][1 * 2048 + tid * 8]); \
    gl2lds16(Bbase + (size_t)2 * 32 * CD + (kt) * 64, &Bls[buf][2 * 2048 + tid * 8]); \
    gl2lds16(Bbase + (size_t)3 * 32 * CD + (kt) * 64, &Bls[buf][3 * 2048 + tid * 8]); \
  } while (0)

  PSTG(0, 0);
  __syncthreads();
  const int NKT = CD / 64;  // 12
  for (int kt = 0; kt < NKT; ++kt) {
    const int cur = kt & 1;
    if (kt + 1 < NKT) PSTG(cur ^ 1, kt + 1);
    bf16x8 bfr[4][2];
#pragma unroll
    for (int j = 0; j < 4; ++j) {
      const int Bcol = wc + j * 16 + cl;
      const int sw = (Bcol & 7) << 3;
      bfr[j][0] = *(const bf16x8*)&Bls[cur][Bcol * 64 + ((g * 8) ^ sw)];
      bfr[j][1] = *(const bf16x8*)&Bls[cur][Bcol * 64 + ((32 + g * 8) ^ sw)];
    }
    __builtin_amdgcn_s_setprio(1);
#pragma unroll
    for (int i = 0; i < 4; ++i) {
      const int Arow = wr + i * 16 + cl;
      const int sw = (Arow & 7) << 3;
      bf16x8 a0 = *(const bf16x8*)&Als[cur][Arow * 64 + ((g * 8) ^ sw)];
      bf16x8 a1 = *(const bf16x8*)&Als[cur][Arow * 64 + ((32 + g * 8) ^ sw)];
#pragma unroll
      for (int j = 0; j < 4; ++j) {
        acc[i][j] = MFMA(a0, bfr[j][0], acc[i][j]);
        acc[i][j] = MFMA(a1, bfr[j][1], acc[i][j]);
      }
    }
    __builtin_amdgcn_s_setprio(0);
    __syncthreads();
  }
#undef PSTG

  const int j0 = bn * 128 + wc;
  float pb4[4];
#pragma unroll
  for (int j = 0; j < 4; ++j) pb4[j] = bias[j0 + j * 16 + cl];
#pragma unroll
  for (int i = 0; i < 4; ++i) {
#pragma unroll
    for (int r = 0; r < 4; ++r) {
      const int m = bm * 128 + wr + i * 16 + g * 4 + r;
      float* orow = out + (size_t)m * CD + j0;
#pragma unroll
      for (int j = 0; j < 4; ++j) orow[j * 16 + cl] = acc[i][j][r] + pb4[j];
    }
  }
}

extern "C" void kernel_launch(void* const* d_in, const int* in_sizes, int n_in,
                              void* d_out, int out_size, void* d_ws, size_t ws_size,
                              hipStream_t stream) {
  const float* x = (const float*)d_in[0];
  const float* qkv_w = (const float*)d_in[1];
  const float* qkv_b = (const float*)d_in[2];
  const float* proj_w = (const float*)d_in[3];
  const float* proj_b = (const float*)d_in[4];
  const float* q_gamma = (const float*)d_in[5];
  const float* q_beta = (const float*)d_in[6];
  const float* k_gamma = (const float*)d_in[7];
  const float* k_beta = (const float*)d_in[8];
  float* out = (float*)d_out;

  char* w = (char*)d_ws;
  unsigned short* Xb = (unsigned short*)w; w += (size_t)MROWS * CD * 2;
  unsigned short* Wq = (unsigned short*)w; w += (size_t)NQKV * CD * 2;
  unsigned short* Wp = (unsigned short*)w; w += (size_t)CD * CD * 2;
  unsigned short* Qo = (unsigned short*)w; w += (size_t)BB * NH * SEQ * DH * 2;
  unsigned short* Ko = (unsigned short*)w; w += (size_t)BB * NH * SEQ * DH * 2;
  unsigned short* Vt = (unsigned short*)w; w += (size_t)BB * NH * SEQ * DH * 2;  // [b,h,d,n]
  unsigned short* Ob = (unsigned short*)w; w += (size_t)MROWS * CD * 2;

  cvt_bf16<<<MROWS * CD / 1024, 256, 0, stream>>>(x, Xb, MROWS * CD / 4);
  cvt_bf16<<<NQKV * CD / 1024, 256, 0, stream>>>(qkv_w, Wq, NQKV * CD / 4);
  cvt_bf16<<<CD * CD / 1024, 256, 0, stream>>>(proj_w, Wp, CD * CD / 4);

  qkv_gemm<<<(MROWS / 128) * (NQKV / 128), 256, 0, stream>>>(
      Xb, Wq, qkv_b, q_gamma, q_beta, k_gamma, k_beta, Qo, Ko, Vt);

  attn_fwd<<<SEQ / 128 * BB * NH, 256, 0, stream>>>(Qo, Ko, Vt, Ob);

  proj_gemm<<<dim3(MROWS / 128, CD / 128), 256, 0, stream>>>(Ob, Wp, proj_b, out);
}

// Round 11
// 154.809 us; speedup vs baseline: 1.2180x; 1.2180x over previous
//
#include <hip/hip_runtime.h>
#include <hip/hip_bf16.h>
#include <cstdint>
#include <cstddef>

#define BB 4
#define SEQ 2048
#define CD 768
#define NH 12
#define DH 64
#define MROWS (BB*SEQ)      // 8192
#define NQKV (3*CD)         // 2304

typedef float f32x4 __attribute__((ext_vector_type(4)));
typedef float f32x16 __attribute__((ext_vector_type(16)));
typedef short bf16x8 __attribute__((ext_vector_type(8)));

static __device__ __forceinline__ unsigned short f2bf(float f) {
  union { float f; unsigned int u; } cv; cv.f = f;
  unsigned int u = cv.u;
  unsigned int r = (u + 0x7FFFu + ((u >> 16) & 1u)) >> 16;
  return (unsigned short)r;
}

// raw v_exp_f32: our exponents are bounded (|x| <= ~23), no OCML fixups needed
static __device__ __forceinline__ float fexp2(float x) {
#if __has_builtin(__builtin_amdgcn_exp2f)
  return __builtin_amdgcn_exp2f(x);
#else
  float r; asm("v_exp_f32 %0, %1" : "=v"(r) : "v"(x)); return r;
#endif
}

#define GAS __attribute__((address_space(1)))
#define LAS __attribute__((address_space(3)))
static __device__ __forceinline__ void gl2lds16(const void* g, void* l) {
  __builtin_amdgcn_global_load_lds((const GAS void*)g, (LAS void*)l, 16, 0, 0);
}

#define MFMA(a, b, c) __builtin_amdgcn_mfma_f32_16x16x32_bf16((a), (b), (c), 0, 0, 0)
#define MFMA32(a, b, c) __builtin_amdgcn_mfma_f32_32x32x16_bf16((a), (b), (c), 0, 0, 0)
#define PACKBF(dst, x, y) asm("v_cvt_pk_bf16_f32 %0, %1, %2" : "=v"(dst) : "v"(x), "v"(y))
#define SWAP32(a, b) asm("v_permlane32_swap_b32 %0, %1" : "+v"(a), "+v"(b))

// 0.125 (1/sqrt(Dh)) * log2(e): folded into Q's gamma/beta so softmax uses exp2 directly.
// With LN'd q,k scores are bounded (|log2 score| <= 11.5) -> no max subtraction needed.
#define QSC 0.18033688011112042f

// ---------------- fp32 -> bf16 convert ----------------
__global__ __launch_bounds__(256) void cvt_bf16(const float* __restrict__ in,
                                                unsigned short* __restrict__ out, int n4) {
  int i = blockIdx.x * 256 + threadIdx.x;
  if (i >= n4) return;
  float4 v = reinterpret_cast<const float4*>(in)[i];
  unsigned int lo = (unsigned int)f2bf(v.x) | ((unsigned int)f2bf(v.y) << 16);
  unsigned int hi = (unsigned int)f2bf(v.z) | ((unsigned int)f2bf(v.w) << 16);
  reinterpret_cast<uint2*>(out)[i] = make_uint2(lo, hi);
}

// ---------------- QKV GEMM: 128x128 tile, BK=64, 4 waves, swizzled LDS ----------------
__global__ __launch_bounds__(256) void qkv_gemm(
    const unsigned short* __restrict__ Xb, const unsigned short* __restrict__ Wb,
    const float* __restrict__ bias,
    const float* __restrict__ qg, const float* __restrict__ qbt,
    const float* __restrict__ kg, const float* __restrict__ kbt,
    unsigned short* __restrict__ Qo, unsigned short* __restrict__ Ko,
    unsigned short* __restrict__ Vt) {
  __shared__ unsigned short Als[2][128 * 64];   // 32KB
  __shared__ unsigned short Bls[2][128 * 64];   // 32KB
  const int tid = threadIdx.x;
  const int wid = tid >> 6, lane = tid & 63;
  const int g = lane >> 4, cl = lane & 15;
  const int wr = (wid >> 1) * 64, wc = (wid & 1) * 64;

  // XCD-bijective swizzle: grid 1152 = 8 * 144; contiguous wgid share bm (A-panel L2 reuse)
  const int wg = blockIdx.x;
  const int wgid = (wg & 7) * 144 + (wg >> 3);
  const int bm = wgid / 18, bn = wgid % 18;

  f32x4 acc[4][4] = {};

  const int srow = tid >> 3;                      // 0..31
  const int scol = ((tid & 7) ^ (srow & 7)) * 8;  // pre-swizzled source col
  const unsigned short* Abase = Xb + (size_t)(bm * 128 + srow) * CD + scol;
  const unsigned short* Bbase = Wb + (size_t)(bn * 128 + srow) * CD + scol;

#define QSTG(buf, kt)                                                         \
  do {                                                                        \
    gl2lds16(Abase + (size_t)0 * 32 * CD + (kt) * 64, &Als[buf][0 * 2048 + tid * 8]); \
    gl2lds16(Abase + (size_t)1 * 32 * CD + (kt) * 64, &Als[buf][1 * 2048 + tid * 8]); \
    gl2lds16(Abase + (size_t)2 * 32 * CD + (kt) * 64, &Als[buf][2 * 2048 + tid * 8]); \
    gl2lds16(Abase + (size_t)3 * 32 * CD + (kt) * 64, &Als[buf][3 * 2048 + tid * 8]); \
    gl2lds16(Bbase + (size_t)0 * 32 * CD + (kt) * 64, &Bls[buf][0 * 2048 + tid * 8]); \
    gl2lds16(Bbase + (size_t)1 * 32 * CD + (kt) * 64, &Bls[buf][1 * 2048 + tid * 8]); \
    gl2lds16(Bbase + (size_t)2 * 32 * CD + (kt) * 64, &Bls[buf][2 * 2048 + tid * 8]); \
    gl2lds16(Bbase + (size_t)3 * 32 * CD + (kt) * 64, &Bls[buf][3 * 2048 + tid * 8]); \
  } while (0)

  QSTG(0, 0);
  __syncthreads();
  const int NKT = CD / 64;  // 12
  for (int kt = 0; kt < NKT; ++kt) {
    const int cur = kt & 1;
    if (kt + 1 < NKT) QSTG(cur ^ 1, kt + 1);
    bf16x8 bfr[4][2];
#pragma unroll
    for (int j = 0; j < 4; ++j) {
      const int Bcol = wc + j * 16 + cl;
      const int sw = (Bcol & 7) << 3;
      bfr[j][0] = *(const bf16x8*)&Bls[cur][Bcol * 64 + ((g * 8) ^ sw)];
      bfr[j][1] = *(const bf16x8*)&Bls[cur][Bcol * 64 + ((32 + g * 8) ^ sw)];
    }
    __builtin_amdgcn_s_setprio(1);
#pragma unroll
    for (int i = 0; i < 4; ++i) {
      const int Arow = wr + i * 16 + cl;
      const int sw = (Arow & 7) << 3;
      bf16x8 a0 = *(const bf16x8*)&Als[cur][Arow * 64 + ((g * 8) ^ sw)];
      bf16x8 a1 = *(const bf16x8*)&Als[cur][Arow * 64 + ((32 + g * 8) ^ sw)];
#pragma unroll
      for (int j = 0; j < 4; ++j) {
        acc[i][j] = MFMA(a0, bfr[j][0], acc[i][j]);
        acc[i][j] = MFMA(a1, bfr[j][1], acc[i][j]);
      }
    }
    __builtin_amdgcn_s_setprio(0);
    __syncthreads();
  }
#undef QSTG

  const int j0 = bn * 128 + wc;
  const int t = j0 / CD;
  const int h = (j0 % CD) / DH;
  float bia[4], gam[4] = {0, 0, 0, 0}, bet[4] = {0, 0, 0, 0};
#pragma unroll
  for (int j = 0; j < 4; ++j) {
    int d = j * 16 + cl;
    bia[j] = bias[j0 + d];
    if (t == 0) { gam[j] = qg[d] * QSC; bet[j] = qbt[d] * QSC; }
    else if (t == 1) { gam[j] = kg[d]; bet[j] = kbt[d]; }
  }

  if (t == 2) {
#pragma unroll
    for (int i = 0; i < 4; ++i) {
      const int mrow = bm * 128 + wr + i * 16 + g * 4;
      const int b = mrow >> 11, nn = mrow & 2047;
#pragma unroll
      for (int j = 0; j < 4; ++j) {
        const int d = j * 16 + cl;
        unsigned int lo = (unsigned int)f2bf(acc[i][j][0] + bia[j]) |
                          ((unsigned int)f2bf(acc[i][j][1] + bia[j]) << 16);
        unsigned int hi2 = (unsigned int)f2bf(acc[i][j][2] + bia[j]) |
                           ((unsigned int)f2bf(acc[i][j][3] + bia[j]) << 16);
        *reinterpret_cast<uint2*>(&Vt[((size_t)(b * NH + h) * DH + d) * SEQ + nn]) =
            make_uint2(lo, hi2);
      }
    }
    return;
  }

  unsigned short* Out = (t == 0) ? Qo : Ko;
#pragma unroll
  for (int i = 0; i < 4; ++i) {
#pragma unroll
    for (int r = 0; r < 4; ++r) {
      float vj[4];
#pragma unroll
      for (int j = 0; j < 4; ++j) vj[j] = acc[i][j][r] + bia[j];
      const int m = bm * 128 + wr + i * 16 + g * 4 + r;
      const int b = m >> 11, n = m & 2047;
      size_t base = ((size_t)(b * NH + h) * SEQ + n) * DH;
      float s = vj[0] + vj[1] + vj[2] + vj[3];
      float ss = vj[0] * vj[0] + vj[1] * vj[1] + vj[2] * vj[2] + vj[3] * vj[3];
#pragma unroll
      for (int msk = 1; msk < 16; msk <<= 1) {
        s += __shfl_xor(s, msk, 64);
        ss += __shfl_xor(ss, msk, 64);
      }
      float mu = s * (1.0f / 64.0f);
      float var = ss * (1.0f / 64.0f) - mu * mu;
      float rstd = rsqrtf(var + 1e-5f);
#pragma unroll
      for (int j = 0; j < 4; ++j)
        Out[base + j * 16 + cl] = f2bf((vj[j] - mu) * rstd * gam[j] + bet[j]);
    }
  }
}

// ---------------- Flash attention: swapped QK^T, KVBLK=128, LDS-staged K and V ----------------
// R8 structure (4 waves x 32 q-rows, K+V via global_load_lds, both-sides XOR swizzle),
// with 128-key tiles: ONE barrier + vmcnt drain per 128 keys (two 64-key compute sub-steps).
// K tile [128][64] (128B rows, (row&7) swizzle); V^T tile [64][128] (256B rows, 16-slot
// (d&15) swizzle). Scores bounded -> no-max softmax; l via ones-MFMA.
__global__ __launch_bounds__(256, 3) void attn_fwd(
    const unsigned short* __restrict__ Qb, const unsigned short* __restrict__ Kb,
    const unsigned short* __restrict__ Vtb, unsigned short* __restrict__ Ob) {
  __shared__ unsigned short kl[2][128 * 64];   // 32KB
  __shared__ unsigned short vt[2][64 * 128];   // 32KB
  const int tid = threadIdx.x, wave = tid >> 6, lane = tid & 63;
  const int q32 = lane & 31, hi = lane >> 5;

  // XCD swizzle (T1): wg%8 = XCD; each XCD owns a contiguous chunk of (bh, qb) space
  const int wg = blockIdx.x;
  const int lin = (wg & 7) * 96 + (wg >> 3);   // 768 = 8 * 96, bijective
  const int bh = lin >> 4;
  const int qbase = (lin & 15) * 128 + wave * 32;

  const unsigned short* qrow = Qb + ((size_t)bh * SEQ + qbase + q32) * DH + hi * 8;
  bf16x8 qf[4];
#pragma unroll
  for (int dc = 0; dc < 4; ++dc) qf[dc] = *(const bf16x8*)&qrow[dc * 16];

  const unsigned short* Kh = Kb + (size_t)bh * SEQ * DH;
  const unsigned short* Vth = Vtb + (size_t)bh * DH * SEQ;

  // K staging: pass p covers rows p*32 + (tid>>3); source col pre-swizzled by (row&7)
  const int sr8 = tid >> 3;
  const int sck = 8 * ((tid & 7) ^ (sr8 & 7));
  // V staging: pass p covers rows p*16 + (tid>>4); source col-slot pre-swizzled by (row&15)
  const int dv = tid >> 4;
  const int scv = 8 * ((tid & 15) ^ dv);

  const int ksw = (q32 & 7) << 3;     // K read swizzle (8 slots of 16B per 128B row)
  const int vswm = (q32 & 15);        // V read swizzle (16 slots of 16B per 256B row)

  const short oneb = (short)0x3F80;  // bf16 1.0
  const bf16x8 onesv = {oneb, oneb, oneb, oneb, oneb, oneb, oneb, oneb};

#define ASTAGE(buf, kb0)                                                          \
  do {                                                                            \
    gl2lds16(&Kh[(size_t)((kb0) + sr8) * DH + sck],       &kl[buf][tid * 8]);     \
    gl2lds16(&Kh[(size_t)((kb0) + 32 + sr8) * DH + sck],  &kl[buf][2048 + tid * 8]); \
    gl2lds16(&Kh[(size_t)((kb0) + 64 + sr8) * DH + sck],  &kl[buf][4096 + tid * 8]); \
    gl2lds16(&Kh[(size_t)((kb0) + 96 + sr8) * DH + sck],  &kl[buf][6144 + tid * 8]); \
    gl2lds16(&Vth[(size_t)dv * SEQ + (kb0) + scv],        &vt[buf][tid * 8]);     \
    gl2lds16(&Vth[(size_t)(16 + dv) * SEQ + (kb0) + scv], &vt[buf][2048 + tid * 8]); \
    gl2lds16(&Vth[(size_t)(32 + dv) * SEQ + (kb0) + scv], &vt[buf][4096 + tid * 8]); \
    gl2lds16(&Vth[(size_t)(48 + dv) * SEQ + (kb0) + scv], &vt[buf][6144 + tid * 8]); \
  } while (0)

  f32x16 o0 = {}, o1 = {}, ol = {};

  ASTAGE(0, 0);
  __syncthreads();
  const int NT = SEQ / 128;  // 16
#pragma unroll 2
  for (int it = 0; it < NT; ++it) {
    const int cur = it & 1;
    if (it + 1 < NT) ASTAGE(cur ^ 1, (it + 1) * 128);

#pragma unroll
    for (int sub = 0; sub < 2; ++sub) {
      const int kb = sub * 64;

      // S^T = K . Q^T for keys kb..kb+63
      f32x16 s0 = {}, s1 = {};
      __builtin_amdgcn_s_setprio(1);
#pragma unroll
      for (int dc = 0; dc < 4; ++dc) {
        const int colb = dc * 16 + hi * 8;
        bf16x8 kf0 = *(const bf16x8*)&kl[cur][(kb + q32) * 64 + (colb ^ ksw)];
        bf16x8 kf1 = *(const bf16x8*)&kl[cur][(kb + 32 + q32) * 64 + (colb ^ ksw)];
        s0 = MFMA32(kf0, qf[dc], s0);
        s1 = MFMA32(kf1, qf[dc], s1);
      }
      __builtin_amdgcn_s_setprio(0);

      // P = exp2(S) directly (bounded scores, no max)
#pragma unroll
      for (int r = 0; r < 16; ++r) {
        s0[r] = fexp2(s0[r]);
        s1[r] = fexp2(s1[r]);
      }

      // P -> bf16 A-frags in-register
      bf16x8 pav[4];
#pragma unroll
      for (int c = 0; c < 4; ++c) {
        const int b = 8 * (c & 1);
        unsigned int wA0, wA1, wB0, wB1;
        if (c < 2) {
          PACKBF(wA0, s0[b + 0], s0[b + 1]); PACKBF(wA1, s0[b + 2], s0[b + 3]);
          PACKBF(wB0, s0[b + 4], s0[b + 5]); PACKBF(wB1, s0[b + 6], s0[b + 7]);
        } else {
          PACKBF(wA0, s1[b + 0], s1[b + 1]); PACKBF(wA1, s1[b + 2], s1[b + 3]);
          PACKBF(wB0, s1[b + 4], s1[b + 5]); PACKBF(wB1, s1[b + 6], s1[b + 7]);
        }
        SWAP32(wA0, wB0);
        SWAP32(wA1, wB1);
        union { unsigned int w[4]; bf16x8 v; } u;
        u.w[0] = wA0; u.w[1] = wA1; u.w[2] = wB0; u.w[3] = wB1;
        pav[c] = u.v;
      }

      // PV: O[q][d] += P . V^T ; V^T rows d=q32 / 32+q32, cols kb + c*16 + hi*8
      __builtin_amdgcn_s_setprio(1);
#pragma unroll
      for (int c = 0; c < 4; ++c) {
        const int slot = (kb >> 3) + c * 2 + hi;     // 16B-slot index within 256B row
        bf16x8 vf0 = *(const bf16x8*)&vt[cur][q32 * 128 + (slot ^ vswm) * 8];
        bf16x8 vf1 = *(const bf16x8*)&vt[cur][(32 + q32) * 128 + (slot ^ vswm) * 8];
        o0 = MFMA32(pav[c], vf0, o0);
        o1 = MFMA32(pav[c], vf1, o1);
        ol = MFMA32(pav[c], onesv, ol);
      }
      __builtin_amdgcn_s_setprio(0);
    }
    __syncthreads();
  }
#undef ASTAGE

  const int b = bh / NH, h = bh % NH;
#pragma unroll
  for (int r = 0; r < 16; ++r) {
    const int qq = (r & 3) + 8 * (r >> 2) + 4 * hi;
    const float iv = __builtin_amdgcn_rcpf(ol[r]);
    size_t base = ((size_t)(b * SEQ + qbase + qq)) * CD + h * DH;
    Ob[base + q32] = f2bf(o0[r] * iv);
    Ob[base + 32 + q32] = f2bf(o1[r] * iv);
  }
}

// ---------------- Proj GEMM: 128x128 tile, BK=64, swizzled LDS, fp32 out ----------------
__global__ __launch_bounds__(256) void proj_gemm(
    const unsigned short* __restrict__ Ab, const unsigned short* __restrict__ Wb,
    const float* __restrict__ bias, float* __restrict__ out) {
  __shared__ unsigned short Als[2][128 * 64];   // 32KB
  __shared__ unsigned short Bls[2][128 * 64];   // 32KB
  const int tid = threadIdx.x;
  const int wid = tid >> 6, lane = tid & 63;
  const int g = lane >> 4, cl = lane & 15;
  const int bm = blockIdx.x, bn = blockIdx.y;
  const int wr = (wid >> 1) * 64, wc = (wid & 1) * 64;

  f32x4 acc[4][4] = {};

  const int srow = tid >> 3;                      // 0..31
  const int scol = ((tid & 7) ^ (srow & 7)) * 8;
  const unsigned short* Abase = Ab + (size_t)(bm * 128 + srow) * CD + scol;
  const unsigned short* Bbase = Wb + (size_t)(bn * 128 + srow) * CD + scol;

#define PSTG(buf, kt)                                                         \
  do {                                                                        \
    gl2lds16(Abase + (size_t)0 * 32 * CD + (kt) * 64, &Als[buf][0 * 2048 + tid * 8]); \
    gl2lds16(Abase + (size_t)1 * 32 * CD + (kt) * 64, &Als[buf][1 * 2048 + tid * 8]); \
    gl2lds16(Abase + (size_t)2 * 32 * CD + (kt) * 64, &Als[buf][2 * 2048 + tid * 8]); \
    gl2lds16(Abase + (size_t)3 * 32 * CD + (kt) * 64, &Als[buf][3 * 2048 + tid * 8]); \
    gl2lds16(Bbase + (size_t)0 * 32 * CD + (kt) * 64, &Bls[buf][0 * 2048 + tid * 8]); \
    gl2lds16(Bbase + (size_t)1 * 32 * CD + (kt) * 64, &Bls[buf][1 * 2048 + tid * 8]); \
    gl2lds16(Bbase + (size_t)2 * 32 * CD + (kt) * 64, &Bls[buf][2 * 2048 + tid * 8]); \
    gl2lds16(Bbase + (size_t)3 * 32 * CD + (kt) * 64, &Bls[buf][3 * 2048 + tid * 8]); \
  } while (0)

  PSTG(0, 0);
  __syncthreads();
  const int NKT = CD / 64;  // 12
  for (int kt = 0; kt < NKT; ++kt) {
    const int cur = kt & 1;
    if (kt + 1 < NKT) PSTG(cur ^ 1, kt + 1);
    bf16x8 bfr[4][2];
#pragma unroll
    for (int j = 0; j < 4; ++j) {
      const int Bcol = wc + j * 16 + cl;
      const int sw = (Bcol & 7) << 3;
      bfr[j][0] = *(const bf16x8*)&Bls[cur][Bcol * 64 + ((g * 8) ^ sw)];
      bfr[j][1] = *(const bf16x8*)&Bls[cur][Bcol * 64 + ((32 + g * 8) ^ sw)];
    }
    __builtin_amdgcn_s_setprio(1);
#pragma unroll
    for (int i = 0; i < 4; ++i) {
      const int Arow = wr + i * 16 + cl;
      const int sw = (Arow & 7) << 3;
      bf16x8 a0 = *(const bf16x8*)&Als[cur][Arow * 64 + ((g * 8) ^ sw)];
      bf16x8 a1 = *(const bf16x8*)&Als[cur][Arow * 64 + ((32 + g * 8) ^ sw)];
#pragma unroll
      for (int j = 0; j < 4; ++j) {
        acc[i][j] = MFMA(a0, bfr[j][0], acc[i][j]);
        acc[i][j] = MFMA(a1, bfr[j][1], acc[i][j]);
      }
    }
    __builtin_amdgcn_s_setprio(0);
    __syncthreads();
  }
#undef PSTG

  const int j0 = bn * 128 + wc;
  float pb4[4];
#pragma unroll
  for (int j = 0; j < 4; ++j) pb4[j] = bias[j0 + j * 16 + cl];
#pragma unroll
  for (int i = 0; i < 4; ++i) {
#pragma unroll
    for (int r = 0; r < 4; ++r) {
      const int m = bm * 128 + wr + i * 16 + g * 4 + r;
      float* orow = out + (size_t)m * CD + j0;
#pragma unroll
      for (int j = 0; j < 4; ++j) orow[j * 16 + cl] = acc[i][j][r] + pb4[j];
    }
  }
}

extern "C" void kernel_launch(void* const* d_in, const int* in_sizes, int n_in,
                              void* d_out, int out_size, void* d_ws, size_t ws_size,
                              hipStream_t stream) {
  const float* x = (const float*)d_in[0];
  const float* qkv_w = (const float*)d_in[1];
  const float* qkv_b = (const float*)d_in[2];
  const float* proj_w = (const float*)d_in[3];
  const float* proj_b = (const float*)d_in[4];
  const float* q_gamma = (const float*)d_in[5];
  const float* q_beta = (const float*)d_in[6];
  const float* k_gamma = (const float*)d_in[7];
  const float* k_beta = (const float*)d_in[8];
  float* out = (float*)d_out;

  char* w = (char*)d_ws;
  unsigned short* Xb = (unsigned short*)w; w += (size_t)MROWS * CD * 2;
  unsigned short* Wq = (unsigned short*)w; w += (size_t)NQKV * CD * 2;
  unsigned short* Wp = (unsigned short*)w; w += (size_t)CD * CD * 2;
  unsigned short* Qo = (unsigned short*)w; w += (size_t)BB * NH * SEQ * DH * 2;
  unsigned short* Ko = (unsigned short*)w; w += (size_t)BB * NH * SEQ * DH * 2;
  unsigned short* Vt = (unsigned short*)w; w += (size_t)BB * NH * SEQ * DH * 2;  // [b,h,d,n]
  unsigned short* Ob = (unsigned short*)w; w += (size_t)MROWS * CD * 2;

  cvt_bf16<<<MROWS * CD / 1024, 256, 0, stream>>>(x, Xb, MROWS * CD / 4);
  cvt_bf16<<<NQKV * CD / 1024, 256, 0, stream>>>(qkv_w, Wq, NQKV * CD / 4);
  cvt_bf16<<<CD * CD / 1024, 256, 0, stream>>>(proj_w, Wp, CD * CD / 4);

  qkv_gemm<<<(MROWS / 128) * (NQKV / 128), 256, 0, stream>>>(
      Xb, Wq, qkv_b, q_gamma, q_beta, k_gamma, k_beta, Qo, Ko, Vt);

  attn_fwd<<<SEQ / 128 * BB * NH, 256, 0, stream>>>(Qo, Ko, Vt, Ob);

  proj_gemm<<<dim3(MROWS / 128, CD / 128), 256, 0, stream>>>(Ob, Wp, proj_b, out);
}

// Round 12
// 145.248 us; speedup vs baseline: 1.2982x; 1.0658x over previous
//
#include <hip/hip_runtime.h>
#include <hip/hip_bf16.h>
#include <cstdint>
#include <cstddef>

#define BB 4
#define SEQ 2048
#define CD 768
#define NH 12
#define DH 64
#define MROWS (BB*SEQ)      // 8192
#define NQKV (3*CD)         // 2304

typedef float f32x4 __attribute__((ext_vector_type(4)));
typedef float f32x16 __attribute__((ext_vector_type(16)));
typedef short bf16x8 __attribute__((ext_vector_type(8)));

static __device__ __forceinline__ unsigned short f2bf(float f) {
  union { float f; unsigned int u; } cv; cv.f = f;
  unsigned int u = cv.u;
  unsigned int r = (u + 0x7FFFu + ((u >> 16) & 1u)) >> 16;
  return (unsigned short)r;
}

// raw v_exp_f32: our exponents are bounded (|x| <= ~23), no OCML fixups needed
static __device__ __forceinline__ float fexp2(float x) {
#if __has_builtin(__builtin_amdgcn_exp2f)
  return __builtin_amdgcn_exp2f(x);
#else
  float r; asm("v_exp_f32 %0, %1" : "=v"(r) : "v"(x)); return r;
#endif
}

#define GAS __attribute__((address_space(1)))
#define LAS __attribute__((address_space(3)))
static __device__ __forceinline__ void gl2lds16(const void* g, void* l) {
  __builtin_amdgcn_global_load_lds((const GAS void*)g, (LAS void*)l, 16, 0, 0);
}

#define MFMA(a, b, c) __builtin_amdgcn_mfma_f32_16x16x32_bf16((a), (b), (c), 0, 0, 0)
#define MFMA32(a, b, c) __builtin_amdgcn_mfma_f32_32x32x16_bf16((a), (b), (c), 0, 0, 0)
#define PACKBF(dst, x, y) asm("v_cvt_pk_bf16_f32 %0, %1, %2" : "=v"(dst) : "v"(x), "v"(y))
#define SWAP32(a, b) asm("v_permlane32_swap_b32 %0, %1" : "+v"(a), "+v"(b))

// 0.125 (1/sqrt(Dh)) * log2(e): folded into Q's gamma/beta so softmax uses exp2 directly.
// With LN'd q,k scores are bounded (|log2 score| <= 11.5) -> no max subtraction needed.
#define QSC 0.18033688011112042f

// ---------------- fp32 -> bf16 convert ----------------
__global__ __launch_bounds__(256) void cvt_bf16(const float* __restrict__ in,
                                                unsigned short* __restrict__ out, int n4) {
  int i = blockIdx.x * 256 + threadIdx.x;
  if (i >= n4) return;
  float4 v = reinterpret_cast<const float4*>(in)[i];
  unsigned int lo = (unsigned int)f2bf(v.x) | ((unsigned int)f2bf(v.y) << 16);
  unsigned int hi = (unsigned int)f2bf(v.z) | ((unsigned int)f2bf(v.w) << 16);
  reinterpret_cast<uint2*>(out)[i] = make_uint2(lo, hi);
}

// ---------------- QKV GEMM: 128x128 tile, BK=64, 4 waves, swizzled LDS ----------------
__global__ __launch_bounds__(256) void qkv_gemm(
    const unsigned short* __restrict__ Xb, const unsigned short* __restrict__ Wb,
    const float* __restrict__ bias,
    const float* __restrict__ qg, const float* __restrict__ qbt,
    const float* __restrict__ kg, const float* __restrict__ kbt,
    unsigned short* __restrict__ Qo, unsigned short* __restrict__ Ko,
    unsigned short* __restrict__ Vt) {
  __shared__ unsigned short Als[2][128 * 64];   // 32KB
  __shared__ unsigned short Bls[2][128 * 64];   // 32KB
  const int tid = threadIdx.x;
  const int wid = tid >> 6, lane = tid & 63;
  const int g = lane >> 4, cl = lane & 15;
  const int wr = (wid >> 1) * 64, wc = (wid & 1) * 64;

  // XCD-bijective swizzle: grid 1152 = 8 * 144; contiguous wgid share bm (A-panel L2 reuse)
  const int wg = blockIdx.x;
  const int wgid = (wg & 7) * 144 + (wg >> 3);
  const int bm = wgid / 18, bn = wgid % 18;

  f32x4 acc[4][4] = {};

  const int srow = tid >> 3;                      // 0..31
  const int scol = ((tid & 7) ^ (srow & 7)) * 8;  // pre-swizzled source col
  const unsigned short* Abase = Xb + (size_t)(bm * 128 + srow) * CD + scol;
  const unsigned short* Bbase = Wb + (size_t)(bn * 128 + srow) * CD + scol;

#define QSTG(buf, kt)                                                         \
  do {                                                                        \
    gl2lds16(Abase + (size_t)0 * 32 * CD + (kt) * 64, &Als[buf][0 * 2048 + tid * 8]); \
    gl2lds16(Abase + (size_t)1 * 32 * CD + (kt) * 64, &Als[buf][1 * 2048 + tid * 8]); \
    gl2lds16(Abase + (size_t)2 * 32 * CD + (kt) * 64, &Als[buf][2 * 2048 + tid * 8]); \
    gl2lds16(Abase + (size_t)3 * 32 * CD + (kt) * 64, &Als[buf][3 * 2048 + tid * 8]); \
    gl2lds16(Bbase + (size_t)0 * 32 * CD + (kt) * 64, &Bls[buf][0 * 2048 + tid * 8]); \
    gl2lds16(Bbase + (size_t)1 * 32 * CD + (kt) * 64, &Bls[buf][1 * 2048 + tid * 8]); \
    gl2lds16(Bbase + (size_t)2 * 32 * CD + (kt) * 64, &Bls[buf][2 * 2048 + tid * 8]); \
    gl2lds16(Bbase + (size_t)3 * 32 * CD + (kt) * 64, &Bls[buf][3 * 2048 + tid * 8]); \
  } while (0)

  QSTG(0, 0);
  __syncthreads();
  const int NKT = CD / 64;  // 12
  for (int kt = 0; kt < NKT; ++kt) {
    const int cur = kt & 1;
    if (kt + 1 < NKT) QSTG(cur ^ 1, kt + 1);
    bf16x8 bfr[4][2];
#pragma unroll
    for (int j = 0; j < 4; ++j) {
      const int Bcol = wc + j * 16 + cl;
      const int sw = (Bcol & 7) << 3;
      bfr[j][0] = *(const bf16x8*)&Bls[cur][Bcol * 64 + ((g * 8) ^ sw)];
      bfr[j][1] = *(const bf16x8*)&Bls[cur][Bcol * 64 + ((32 + g * 8) ^ sw)];
    }
    __builtin_amdgcn_s_setprio(1);
#pragma unroll
    for (int i = 0; i < 4; ++i) {
      const int Arow = wr + i * 16 + cl;
      const int sw = (Arow & 7) << 3;
      bf16x8 a0 = *(const bf16x8*)&Als[cur][Arow * 64 + ((g * 8) ^ sw)];
      bf16x8 a1 = *(const bf16x8*)&Als[cur][Arow * 64 + ((32 + g * 8) ^ sw)];
#pragma unroll
      for (int j = 0; j < 4; ++j) {
        acc[i][j] = MFMA(a0, bfr[j][0], acc[i][j]);
        acc[i][j] = MFMA(a1, bfr[j][1], acc[i][j]);
      }
    }
    __builtin_amdgcn_s_setprio(0);
    __syncthreads();
  }
#undef QSTG

  const int j0 = bn * 128 + wc;
  const int t = j0 / CD;
  const int h = (j0 % CD) / DH;
  float bia[4], gam[4] = {0, 0, 0, 0}, bet[4] = {0, 0, 0, 0};
#pragma unroll
  for (int j = 0; j < 4; ++j) {
    int d = j * 16 + cl;
    bia[j] = bias[j0 + d];
    if (t == 0) { gam[j] = qg[d] * QSC; bet[j] = qbt[d] * QSC; }
    else if (t == 1) { gam[j] = kg[d]; bet[j] = kbt[d]; }
  }

  if (t == 2) {
#pragma unroll
    for (int i = 0; i < 4; ++i) {
      const int mrow = bm * 128 + wr + i * 16 + g * 4;
      const int b = mrow >> 11, nn = mrow & 2047;
#pragma unroll
      for (int j = 0; j < 4; ++j) {
        const int d = j * 16 + cl;
        unsigned int lo = (unsigned int)f2bf(acc[i][j][0] + bia[j]) |
                          ((unsigned int)f2bf(acc[i][j][1] + bia[j]) << 16);
        unsigned int hi2 = (unsigned int)f2bf(acc[i][j][2] + bia[j]) |
                           ((unsigned int)f2bf(acc[i][j][3] + bia[j]) << 16);
        *reinterpret_cast<uint2*>(&Vt[((size_t)(b * NH + h) * DH + d) * SEQ + nn]) =
            make_uint2(lo, hi2);
      }
    }
    return;
  }

  unsigned short* Out = (t == 0) ? Qo : Ko;
#pragma unroll
  for (int i = 0; i < 4; ++i) {
#pragma unroll
    for (int r = 0; r < 4; ++r) {
      float vj[4];
#pragma unroll
      for (int j = 0; j < 4; ++j) vj[j] = acc[i][j][r] + bia[j];
      const int m = bm * 128 + wr + i * 16 + g * 4 + r;
      const int b = m >> 11, n = m & 2047;
      size_t base = ((size_t)(b * NH + h) * SEQ + n) * DH;
      float s = vj[0] + vj[1] + vj[2] + vj[3];
      float ss = vj[0] * vj[0] + vj[1] * vj[1] + vj[2] * vj[2] + vj[3] * vj[3];
#pragma unroll
      for (int msk = 1; msk < 16; msk <<= 1) {
        s += __shfl_xor(s, msk, 64);
        ss += __shfl_xor(ss, msk, 64);
      }
      float mu = s * (1.0f / 64.0f);
      float var = ss * (1.0f / 64.0f) - mu * mu;
      float rstd = rsqrtf(var + 1e-5f);
#pragma unroll
      for (int j = 0; j < 4; ++j)
        Out[base + j * 16 + cl] = f2bf((vj[j] - mu) * rstd * gam[j] + bet[j]);
    }
  }
}

// ---------------- Flash attention: R8 structure, VALU row-sum (no ones-MFMA) ----------------
// 4 waves x 32 q-rows, KVBLK=64, K+V via global_load_lds, both-sides XOR swizzle.
// No-max softmax (bounded scores) -> l is a lane-local f32 accumulation over all tiles,
// cross-lane + layout exchange done ONCE at the end (saves 4 MFMA32/tile on the matrix pipe).
__global__ __launch_bounds__(256, 3) void attn_fwd(
    const unsigned short* __restrict__ Qb, const unsigned short* __restrict__ Kb,
    const unsigned short* __restrict__ Vtb, unsigned short* __restrict__ Ob) {
  __shared__ unsigned short kl[2][64 * 64];   // [key][d], 128B rows, XOR-swizzled
  __shared__ unsigned short vt[2][64 * 64];   // [d][key], 128B rows, XOR-swizzled
  __shared__ float linv[4][32];
  const int tid = threadIdx.x, wave = tid >> 6, lane = tid & 63;
  const int q32 = lane & 31, hi = lane >> 5;

  // XCD swizzle (T1): wg%8 = XCD; each XCD owns a contiguous chunk of (bh, qb) space
  const int wg = blockIdx.x;
  const int lin = (wg & 7) * 96 + (wg >> 3);   // 768 = 8 * 96, bijective
  const int bh = lin >> 4;
  const int qbase = (lin & 15) * 128 + wave * 32;

  const unsigned short* qrow = Qb + ((size_t)bh * SEQ + qbase + q32) * DH + hi * 8;
  bf16x8 qf[4];
#pragma unroll
  for (int dc = 0; dc < 4; ++dc) qf[dc] = *(const bf16x8*)&qrow[dc * 16];

  const unsigned short* Kh = Kb + (size_t)bh * SEQ * DH;
  const unsigned short* Vth = Vtb + (size_t)bh * DH * SEQ;

  const int sr = tid >> 3;
  const int sc = 8 * ((tid & 7) ^ (sr & 7));
  const int ksw = (q32 & 7) << 3;

#define ASTAGE(buf, kb0)                                                      \
  do {                                                                        \
    gl2lds16(&Kh[(size_t)((kb0) + sr) * DH + sc], &kl[buf][tid * 8]);         \
    gl2lds16(&Kh[(size_t)((kb0) + sr + 32) * DH + sc], &kl[buf][tid * 8 + 2048]); \
    gl2lds16(&Vth[(size_t)sr * SEQ + (kb0) + sc], &vt[buf][tid * 8]);         \
    gl2lds16(&Vth[(size_t)(sr + 32) * SEQ + (kb0) + sc], &vt[buf][tid * 8 + 2048]); \
  } while (0)

  f32x16 o0 = {}, o1 = {};
  float su0 = 0.0f, su1 = 0.0f, su2 = 0.0f, su3 = 0.0f;

  ASTAGE(0, 0);
  __syncthreads();
  const int NT = SEQ / 64;  // 32
#pragma unroll 2
  for (int it = 0; it < NT; ++it) {
    const int cur = it & 1;
    if (it + 1 < NT) ASTAGE(cur ^ 1, (it + 1) * 64);

    f32x16 s0 = {}, s1 = {};
    __builtin_amdgcn_s_setprio(1);
#pragma unroll
    for (int dc = 0; dc < 4; ++dc) {
      const int colb = dc * 16 + hi * 8;
      bf16x8 kf0 = *(const bf16x8*)&kl[cur][q32 * 64 + (colb ^ ksw)];
      bf16x8 kf1 = *(const bf16x8*)&kl[cur][(32 + q32) * 64 + (colb ^ ksw)];
      s0 = MFMA32(kf0, qf[dc], s0);
      s1 = MFMA32(kf1, qf[dc], s1);
    }
    __builtin_amdgcn_s_setprio(0);

    // P = exp2(S) directly (bounded scores, no max); lane-local row-sum accumulation
#pragma unroll
    for (int r = 0; r < 16; r += 4) {
      s0[r + 0] = fexp2(s0[r + 0]); su0 += s0[r + 0];
      s0[r + 1] = fexp2(s0[r + 1]); su1 += s0[r + 1];
      s0[r + 2] = fexp2(s0[r + 2]); su2 += s0[r + 2];
      s0[r + 3] = fexp2(s0[r + 3]); su3 += s0[r + 3];
    }
#pragma unroll
    for (int r = 0; r < 16; r += 4) {
      s1[r + 0] = fexp2(s1[r + 0]); su0 += s1[r + 0];
      s1[r + 1] = fexp2(s1[r + 1]); su1 += s1[r + 1];
      s1[r + 2] = fexp2(s1[r + 2]); su2 += s1[r + 2];
      s1[r + 3] = fexp2(s1[r + 3]); su3 += s1[r + 3];
    }

    // P -> bf16 A-frags in-register
    bf16x8 pav[4];
#pragma unroll
    for (int c = 0; c < 4; ++c) {
      const int b = 8 * (c & 1);
      unsigned int wA0, wA1, wB0, wB1;
      if (c < 2) {
        PACKBF(wA0, s0[b + 0], s0[b + 1]); PACKBF(wA1, s0[b + 2], s0[b + 3]);
        PACKBF(wB0, s0[b + 4], s0[b + 5]); PACKBF(wB1, s0[b + 6], s0[b + 7]);
      } else {
        PACKBF(wA0, s1[b + 0], s1[b + 1]); PACKBF(wA1, s1[b + 2], s1[b + 3]);
        PACKBF(wB0, s1[b + 4], s1[b + 5]); PACKBF(wB1, s1[b + 6], s1[b + 7]);
      }
      SWAP32(wA0, wB0);
      SWAP32(wA1, wB1);
      union { unsigned int w[4]; bf16x8 v; } u;
      u.w[0] = wA0; u.w[1] = wA1; u.w[2] = wB0; u.w[3] = wB1;
      pav[c] = u.v;
    }

    // PV: O[q][d] += P[q][key] . V^T[d][key]
    __builtin_amdgcn_s_setprio(1);
#pragma unroll
    for (int c = 0; c < 4; ++c) {
      const int colb = c * 16 + hi * 8;
      bf16x8 vf0 = *(const bf16x8*)&vt[cur][q32 * 64 + (colb ^ ksw)];
      bf16x8 vf1 = *(const bf16x8*)&vt[cur][(32 + q32) * 64 + (colb ^ ksw)];
      o0 = MFMA32(pav[c], vf0, o0);
      o1 = MFMA32(pav[c], vf1, o1);
    }
    __builtin_amdgcn_s_setprio(0);
    __syncthreads();
  }
#undef ASTAGE

  // l: lane-local partial (half the keys for q=q32) + cross-lane + layout exchange, once
  float lsum = (su0 + su1) + (su2 + su3);
  lsum += __shfl_xor(lsum, 32, 64);
  linv[wave][q32] = __builtin_amdgcn_rcpf(lsum);   // hi pair writes same value
  __syncthreads();

  const int b = bh / NH, h = bh % NH;
#pragma unroll
  for (int r = 0; r < 16; ++r) {
    const int qq = (r & 3) + 8 * (r >> 2) + 4 * hi;
    const float iv = linv[wave][qq];
    size_t base = ((size_t)(b * SEQ + qbase + qq)) * CD + h * DH;
    Ob[base + q32] = f2bf(o0[r] * iv);
    Ob[base + 32 + q32] = f2bf(o1[r] * iv);
  }
}

// ---------------- Proj GEMM: 128x128 tile, BK=64, swizzled LDS, fp32 out ----------------
__global__ __launch_bounds__(256) void proj_gemm(
    const unsigned short* __restrict__ Ab, const unsigned short* __restrict__ Wb,
    const float* __restrict__ bias, float* __restrict__ out) {
  __shared__ unsigned short Als[2][128 * 64];   // 32KB
  __shared__ unsigned short Bls[2][128 * 64];   // 32KB
  const int tid = threadIdx.x;
  const int wid = tid >> 6, lane = tid & 63;
  const int g = lane >> 4, cl = lane & 15;
  const int bm = blockIdx.x, bn = blockIdx.y;
  const int wr = (wid >> 1) * 64, wc = (wid & 1) * 64;

  f32x4 acc[4][4] = {};

  const int srow = tid >> 3;                      // 0..31
  const int scol = ((tid & 7) ^ (srow & 7)) * 8;
  const unsigned short* Abase = Ab + (size_t)(bm * 128 + srow) * CD + scol;
  const unsigned short* Bbase = Wb + (size_t)(bn * 128 + srow) * CD + scol;

#define PSTG(buf, kt)                                                         \
  do {                                                                        \
    gl2lds16(Abase + (size_t)0 * 32 * CD + (kt) * 64, &Als[buf][0 * 2048 + tid * 8]); \
    gl2lds16(Abase + (size_t)1 * 32 * CD + (kt) * 64, &Als[buf][1 * 2048 + tid * 8]); \
    gl2lds16(Abase + (size_t)2 * 32 * CD + (kt) * 64, &Als[buf][2 * 2048 + tid * 8]); \
    gl2lds16(Abase + (size_t)3 * 32 * CD + (kt) * 64, &Als[buf][3 * 2048 + tid * 8]); \
    gl2lds16(Bbase + (size_t)0 * 32 * CD + (kt) * 64, &Bls[buf][0 * 2048 + tid * 8]); \
    gl2lds16(Bbase + (size_t)1 * 32 * CD + (kt) * 64, &Bls[buf][1 * 2048 + tid * 8]); \
    gl2lds16(Bbase + (size_t)2 * 32 * CD + (kt) * 64, &Bls[buf][2 * 2048 + tid * 8]); \
    gl2lds16(Bbase + (size_t)3 * 32 * CD + (kt) * 64, &Bls[buf][3 * 2048 + tid * 8]); \
  } while (0)

  PSTG(0, 0);
  __syncthreads();
  const int NKT = CD / 64;  // 12
  for (int kt = 0; kt < NKT; ++kt) {
    const int cur = kt & 1;
    if (kt + 1 < NKT) PSTG(cur ^ 1, kt + 1);
    bf16x8 bfr[4][2];
#pragma unroll
    for (int j = 0; j < 4; ++j) {
      const int Bcol = wc + j * 16 + cl;
      const int sw = (Bcol & 7) << 3;
      bfr[j][0] = *(const bf16x8*)&Bls[cur][Bcol * 64 + ((g * 8) ^ sw)];
      bfr[j][1] = *(const bf16x8*)&Bls[cur][Bcol * 64 + ((32 + g * 8) ^ sw)];
    }
    __builtin_amdgcn_s_setprio(1);
#pragma unroll
    for (int i = 0; i < 4; ++i) {
      const int Arow = wr + i * 16 + cl;
      const int sw = (Arow & 7) << 3;
      bf16x8 a0 = *(const bf16x8*)&Als[cur][Arow * 64 + ((g * 8) ^ sw)];
      bf16x8 a1 = *(const bf16x8*)&Als[cur][Arow * 64 + ((32 + g * 8) ^ sw)];
#pragma unroll
      for (int j = 0; j < 4; ++j) {
        acc[i][j] = MFMA(a0, bfr[j][0], acc[i][j]);
        acc[i][j] = MFMA(a1, bfr[j][1], acc[i][j]);
      }
    }
    __builtin_amdgcn_s_setprio(0);
    __syncthreads();
  }
#undef PSTG

  const int j0 = bn * 128 + wc;
  float pb4[4];
#pragma unroll
  for (int j = 0; j < 4; ++j) pb4[j] = bias[j0 + j * 16 + cl];
#pragma unroll
  for (int i = 0; i < 4; ++i) {
#pragma unroll
    for (int r = 0; r < 4; ++r) {
      const int m = bm * 128 + wr + i * 16 + g * 4 + r;
      float* orow = out + (size_t)m * CD + j0;
#pragma unroll
      for (int j = 0; j < 4; ++j) orow[j * 16 + cl] = acc[i][j][r] + pb4[j];
    }
  }
}

extern "C" void kernel_launch(void* const* d_in, const int* in_sizes, int n_in,
                              void* d_out, int out_size, void* d_ws, size_t ws_size,
                              hipStream_t stream) {
  const float* x = (const float*)d_in[0];
  const float* qkv_w = (const float*)d_in[1];
  const float* qkv_b = (const float*)d_in[2];
  const float* proj_w = (const float*)d_in[3];
  const float* proj_b = (const float*)d_in[4];
  const float* q_gamma = (const float*)d_in[5];
  const float* q_beta = (const float*)d_in[6];
  const float* k_gamma = (const float*)d_in[7];
  const float* k_beta = (const float*)d_in[8];
  float* out = (float*)d_out;

  char* w = (char*)d_ws;
  unsigned short* Xb = (unsigned short*)w; w += (size_t)MROWS * CD * 2;
  unsigned short* Wq = (unsigned short*)w; w += (size_t)NQKV * CD * 2;
  unsigned short* Wp = (unsigned short*)w; w += (size_t)CD * CD * 2;
  unsigned short* Qo = (unsigned short*)w; w += (size_t)BB * NH * SEQ * DH * 2;
  unsigned short* Ko = (unsigned short*)w; w += (size_t)BB * NH * SEQ * DH * 2;
  unsigned short* Vt = (unsigned short*)w; w += (size_t)BB * NH * SEQ * DH * 2;  // [b,h,d,n]
  unsigned short* Ob = (unsigned short*)w; w += (size_t)MROWS * CD * 2;

  cvt_bf16<<<MROWS * CD / 1024, 256, 0, stream>>>(x, Xb, MROWS * CD / 4);
  cvt_bf16<<<NQKV * CD / 1024, 256, 0, stream>>>(qkv_w, Wq, NQKV * CD / 4);
  cvt_bf16<<<CD * CD / 1024, 256, 0, stream>>>(proj_w, Wp, CD * CD / 4);

  qkv_gemm<<<(MROWS / 128) * (NQKV / 128), 256, 0, stream>>>(
      Xb, Wq, qkv_b, q_gamma, q_beta, k_gamma, k_beta, Qo, Ko, Vt);

  attn_fwd<<<SEQ / 128 * BB * NH, 256, 0, stream>>>(Qo, Ko, Vt, Ob);

  proj_gemm<<<dim3(MROWS / 128, CD / 128), 256, 0, stream>>>(Ob, Wp, proj_b, out);
}

// Round 13
// 133.771 us; speedup vs baseline: 1.4096x; 1.0858x over previous
//
#include <hip/hip_runtime.h>
#include <hip/hip_bf16.h>
#include <cstdint>
#include <cstddef>

#define BB 4
#define SEQ 2048
#define CD 768
#define NH 12
#define DH 64
#define MROWS (BB*SEQ)      // 8192
#define NQKV (3*CD)         // 2304

typedef float f32x4 __attribute__((ext_vector_type(4)));
typedef float f32x16 __attribute__((ext_vector_type(16)));
typedef short bf16x8 __attribute__((ext_vector_type(8)));

static __device__ __forceinline__ unsigned short f2bf(float f) {
  union { float f; unsigned int u; } cv; cv.f = f;
  unsigned int u = cv.u;
  unsigned int r = (u + 0x7FFFu + ((u >> 16) & 1u)) >> 16;
  return (unsigned short)r;
}

// raw v_exp_f32: our exponents are bounded (|x| <= ~23), no OCML fixups needed
static __device__ __forceinline__ float fexp2(float x) {
#if __has_builtin(__builtin_amdgcn_exp2f)
  return __builtin_amdgcn_exp2f(x);
#else
  float r; asm("v_exp_f32 %0, %1" : "=v"(r) : "v"(x)); return r;
#endif
}

#define GAS __attribute__((address_space(1)))
#define LAS __attribute__((address_space(3)))
static __device__ __forceinline__ void gl2lds16(const void* g, void* l) {
  __builtin_amdgcn_global_load_lds((const GAS void*)g, (LAS void*)l, 16, 0, 0);
}

#define MFMA(a, b, c) __builtin_amdgcn_mfma_f32_16x16x32_bf16((a), (b), (c), 0, 0, 0)
#define MFMA32(a, b, c) __builtin_amdgcn_mfma_f32_32x32x16_bf16((a), (b), (c), 0, 0, 0)
#define PACKBF(dst, x, y) asm("v_cvt_pk_bf16_f32 %0, %1, %2" : "=v"(dst) : "v"(x), "v"(y))
#define SWAP32(a, b) asm("v_permlane32_swap_b32 %0, %1" : "+v"(a), "+v"(b))

// 0.125 (1/sqrt(Dh)) * log2(e): folded into Q's gamma/beta so softmax uses exp2 directly.
// With LN'd q,k scores are bounded (|log2 score| <= 11.5) -> no max subtraction needed.
#define QSC 0.18033688011112042f

// ---------------- fp32 -> bf16 convert (x, qkv_w, proj_w in one launch) ----------------
#define CN1 (MROWS * CD / 4)
#define CN2 (CN1 + NQKV * CD / 4)
#define CN3 (CN2 + CD * CD / 4)
__global__ __launch_bounds__(256) void cvt_all(
    const float* __restrict__ x, const float* __restrict__ wq, const float* __restrict__ wp,
    unsigned short* __restrict__ Xb, unsigned short* __restrict__ Wq,
    unsigned short* __restrict__ Wp) {
  int i = blockIdx.x * 256 + threadIdx.x;
  if (i >= CN3) return;
  const float* src;
  unsigned short* dst;
  int k;
  if (i < CN1) { src = x; dst = Xb; k = i; }
  else if (i < CN2) { src = wq; dst = Wq; k = i - CN1; }
  else { src = wp; dst = Wp; k = i - CN2; }
  float4 v = reinterpret_cast<const float4*>(src)[k];
  unsigned int lo = (unsigned int)f2bf(v.x) | ((unsigned int)f2bf(v.y) << 16);
  unsigned int hi = (unsigned int)f2bf(v.z) | ((unsigned int)f2bf(v.w) << 16);
  reinterpret_cast<uint2*>(dst)[k] = make_uint2(lo, hi);
}

// ---------------- QKV GEMM: 128x128 tile, BK=64, 4 waves, swizzled LDS ----------------
// Epilogue: acc -> LDS (f32, slot-XOR swizzled) -> per-thread full-row LN (no shuffles)
// -> fully coalesced 16B stores. t==0 -> LN -> Qo[b,h,n,d]; t==1 -> LN -> Ko; t==2 -> Vt[b,h,d,n].
__global__ __launch_bounds__(256) void qkv_gemm(
    const unsigned short* __restrict__ Xb, const unsigned short* __restrict__ Wb,
    const float* __restrict__ bias,
    const float* __restrict__ qg, const float* __restrict__ qbt,
    const float* __restrict__ kg, const float* __restrict__ kbt,
    unsigned short* __restrict__ Qo, unsigned short* __restrict__ Ko,
    unsigned short* __restrict__ Vt) {
  __shared__ unsigned short smem[4 * 128 * 64];   // 64KB: staging dbuf, then f32 C-buffer
#define ALS(buf) (&smem[(buf) * 8192])
#define BLS(buf) (&smem[16384 + (buf) * 8192])
  const int tid = threadIdx.x;
  const int wid = tid >> 6, lane = tid & 63;
  const int g = lane >> 4, cl = lane & 15;
  const int wr = (wid >> 1) * 64, wc = (wid & 1) * 64;

  // XCD-bijective swizzle: grid 1152 = 8 * 144; contiguous wgid share bm (A-panel L2 reuse)
  const int wg = blockIdx.x;
  const int wgid = (wg & 7) * 144 + (wg >> 3);
  const int bm = wgid / 18, bn = wgid % 18;

  f32x4 acc[4][4] = {};

  const int srow = tid >> 3;                      // 0..31
  const int scol = ((tid & 7) ^ (srow & 7)) * 8;  // pre-swizzled source col
  const unsigned short* Abase = Xb + (size_t)(bm * 128 + srow) * CD + scol;
  const unsigned short* Bbase = Wb + (size_t)(bn * 128 + srow) * CD + scol;

#define QSTG(buf, kt)                                                         \
  do {                                                                        \
    gl2lds16(Abase + (size_t)0 * 32 * CD + (kt) * 64, ALS(buf) + 0 * 2048 + tid * 8); \
    gl2lds16(Abase + (size_t)1 * 32 * CD + (kt) * 64, ALS(buf) + 1 * 2048 + tid * 8); \
    gl2lds16(Abase + (size_t)2 * 32 * CD + (kt) * 64, ALS(buf) + 2 * 2048 + tid * 8); \
    gl2lds16(Abase + (size_t)3 * 32 * CD + (kt) * 64, ALS(buf) + 3 * 2048 + tid * 8); \
    gl2lds16(Bbase + (size_t)0 * 32 * CD + (kt) * 64, BLS(buf) + 0 * 2048 + tid * 8); \
    gl2lds16(Bbase + (size_t)1 * 32 * CD + (kt) * 64, BLS(buf) + 1 * 2048 + tid * 8); \
    gl2lds16(Bbase + (size_t)2 * 32 * CD + (kt) * 64, BLS(buf) + 2 * 2048 + tid * 8); \
    gl2lds16(Bbase + (size_t)3 * 32 * CD + (kt) * 64, BLS(buf) + 3 * 2048 + tid * 8); \
  } while (0)

  QSTG(0, 0);
  __syncthreads();
  const int NKT = CD / 64;  // 12
  for (int kt = 0; kt < NKT; ++kt) {
    const int cur = kt & 1;
    if (kt + 1 < NKT) QSTG(cur ^ 1, kt + 1);
    bf16x8 bfr[4][2];
#pragma unroll
    for (int j = 0; j < 4; ++j) {
      const int Bcol = wc + j * 16 + cl;
      const int sw = (Bcol & 7) << 3;
      bfr[j][0] = *(const bf16x8*)&BLS(cur)[Bcol * 64 + ((g * 8) ^ sw)];
      bfr[j][1] = *(const bf16x8*)&BLS(cur)[Bcol * 64 + ((32 + g * 8) ^ sw)];
    }
    __builtin_amdgcn_s_setprio(1);
#pragma unroll
    for (int i = 0; i < 4; ++i) {
      const int Arow = wr + i * 16 + cl;
      const int sw = (Arow & 7) << 3;
      bf16x8 a0 = *(const bf16x8*)&ALS(cur)[Arow * 64 + ((g * 8) ^ sw)];
      bf16x8 a1 = *(const bf16x8*)&ALS(cur)[Arow * 64 + ((32 + g * 8) ^ sw)];
#pragma unroll
      for (int j = 0; j < 4; ++j) {
        acc[i][j] = MFMA(a0, bfr[j][0], acc[i][j]);
        acc[i][j] = MFMA(a1, bfr[j][1], acc[i][j]);
      }
    }
    __builtin_amdgcn_s_setprio(0);
    __syncthreads();
  }
#undef QSTG

  // ---- LDS-bounce epilogue ----
  // f32 C[128][128] in the (now dead) 64KB staging LDS; 16B-slot XOR swizzle:
  // addr(r,c) = r*128 + ((c>>2 ^ (r&31))<<2) + (c&3)
  float* cb = (float*)smem;
#define CIDX(r, c) ((r) * 128 + (((((c) >> 2)) ^ ((r) & 31)) << 2) + ((c) & 3))
#pragma unroll
  for (int i = 0; i < 4; ++i)
#pragma unroll
    for (int j = 0; j < 4; ++j)
#pragma unroll
      for (int r = 0; r < 4; ++r)
        cb[CIDX(wr + i * 16 + g * 4 + r, wc + j * 16 + cl)] = acc[i][j][r];
  __syncthreads();

  const int t = bn / 6;              // 128 cols per block, 768 per t -> 6 blocks per t
  const int h0 = (bn % 6) * 2;       // 2 heads per block
  const int j0 = bn * 128;

  if (t == 2) {
    // V: thread owns one (h,d) column, half the n-range; column read is conflict-free
    // by XOR rotation; write = coalesced 128B row of Vt[b,h,d,n].
    const int col = tid >> 1, nh = tid & 1;
    const int h = h0 + (col >> 6), d = col & 63;
    const float bia = bias[j0 + col];
    const int m0 = bm * 128;
    const int b = m0 >> 11;
    const int nn0 = (m0 & 2047) + nh * 64;
    unsigned short* dst = &Vt[((size_t)(b * NH + h) * DH + d) * SEQ + nn0];
#pragma unroll
    for (int k8 = 0; k8 < 8; ++k8) {
      union { unsigned short us[8]; uint4 v; } u;
#pragma unroll
      for (int e = 0; e < 8; ++e)
        u.us[e] = f2bf(cb[CIDX(nh * 64 + k8 * 8 + e, col)] + bia);
      *reinterpret_cast<uint4*>(&dst[k8 * 8]) = u.v;
    }
    return;
  }

  // Q/K: thread owns one (n, head) row: lane-local LN (no shuffles), coalesced stores.
  const int nl = tid >> 1, half = tid & 1;
  const int h = h0 + half;
  const int m = bm * 128 + nl;
  const int b = m >> 11, n = m & 2047;
  const float* gmp = (t == 0) ? qg : kg;
  const float* btp = (t == 0) ? qbt : kbt;
  const float sc = (t == 0) ? QSC : 1.0f;
  const float* bi = bias + j0 + half * 64;

  float v[64];
#pragma unroll
  for (int k4 = 0; k4 < 16; ++k4) {
    f32x4 q = *(const f32x4*)&cb[nl * 128 + ((((half * 16 + k4)) ^ (nl & 31)) << 2)];
    float4 b4 = reinterpret_cast<const float4*>(bi)[k4];
    v[k4 * 4 + 0] = q[0] + b4.x;
    v[k4 * 4 + 1] = q[1] + b4.y;
    v[k4 * 4 + 2] = q[2] + b4.z;
    v[k4 * 4 + 3] = q[3] + b4.w;
  }
  float s0 = 0, s1 = 0, s2 = 0, s3 = 0, q0 = 0, q1 = 0, q2 = 0, q3 = 0;
#pragma unroll
  for (int k = 0; k < 64; k += 4) {
    s0 += v[k]; q0 += v[k] * v[k];
    s1 += v[k + 1]; q1 += v[k + 1] * v[k + 1];
    s2 += v[k + 2]; q2 += v[k + 2] * v[k + 2];
    s3 += v[k + 3]; q3 += v[k + 3] * v[k + 3];
  }
  const float sum = (s0 + s1) + (s2 + s3);
  const float ssum = (q0 + q1) + (q2 + q3);
  const float mu = sum * (1.0f / 64.0f);
  const float var = ssum * (1.0f / 64.0f) - mu * mu;
  const float rstd = rsqrtf(var + 1e-5f);

  unsigned short* dst = ((t == 0) ? Qo : Ko) + ((size_t)(b * NH + h) * SEQ + n) * DH;
#pragma unroll
  for (int k8 = 0; k8 < 8; ++k8) {
    float4 gm4 = reinterpret_cast<const float4*>(gmp)[k8 * 2];
    float4 gm4b = reinterpret_cast<const float4*>(gmp)[k8 * 2 + 1];
    float4 bt4 = reinterpret_cast<const float4*>(btp)[k8 * 2];
    float4 bt4b = reinterpret_cast<const float4*>(btp)[k8 * 2 + 1];
    const float* g8 = &gm4.x;
    const float* b8 = &bt4.x;
    union { unsigned short us[8]; uint4 vv; } u;
#pragma unroll
    for (int e = 0; e < 4; ++e) {
      u.us[e] = f2bf(((v[k8 * 8 + e] - mu) * rstd * (&gm4.x)[e] + (&bt4.x)[e]) * sc);
      u.us[4 + e] = f2bf(((v[k8 * 8 + 4 + e] - mu) * rstd * (&gm4b.x)[e] + (&bt4b.x)[e]) * sc);
    }
    (void)g8; (void)b8;
    *reinterpret_cast<uint4*>(&dst[k8 * 8]) = u.vv;
  }
#undef CIDX
#undef ALS
#undef BLS
}

// ---------------- Flash attention: R8 structure, VALU row-sum (no ones-MFMA) ----------------
__global__ __launch_bounds__(256, 3) void attn_fwd(
    const unsigned short* __restrict__ Qb, const unsigned short* __restrict__ Kb,
    const unsigned short* __restrict__ Vtb, unsigned short* __restrict__ Ob) {
  __shared__ unsigned short kl[2][64 * 64];   // [key][d], 128B rows, XOR-swizzled
  __shared__ unsigned short vt[2][64 * 64];   // [d][key], 128B rows, XOR-swizzled
  __shared__ float linv[4][32];
  const int tid = threadIdx.x, wave = tid >> 6, lane = tid & 63;
  const int q32 = lane & 31, hi = lane >> 5;

  const int wg = blockIdx.x;
  const int lin = (wg & 7) * 96 + (wg >> 3);   // 768 = 8 * 96, bijective
  const int bh = lin >> 4;
  const int qbase = (lin & 15) * 128 + wave * 32;

  const unsigned short* qrow = Qb + ((size_t)bh * SEQ + qbase + q32) * DH + hi * 8;
  bf16x8 qf[4];
#pragma unroll
  for (int dc = 0; dc < 4; ++dc) qf[dc] = *(const bf16x8*)&qrow[dc * 16];

  const unsigned short* Kh = Kb + (size_t)bh * SEQ * DH;
  const unsigned short* Vth = Vtb + (size_t)bh * DH * SEQ;

  const int sr = tid >> 3;
  const int sc = 8 * ((tid & 7) ^ (sr & 7));
  const int ksw = (q32 & 7) << 3;

#define ASTAGE(buf, kb0)                                                      \
  do {                                                                        \
    gl2lds16(&Kh[(size_t)((kb0) + sr) * DH + sc], &kl[buf][tid * 8]);         \
    gl2lds16(&Kh[(size_t)((kb0) + sr + 32) * DH + sc], &kl[buf][tid * 8 + 2048]); \
    gl2lds16(&Vth[(size_t)sr * SEQ + (kb0) + sc], &vt[buf][tid * 8]);         \
    gl2lds16(&Vth[(size_t)(sr + 32) * SEQ + (kb0) + sc], &vt[buf][tid * 8 + 2048]); \
  } while (0)

  f32x16 o0 = {}, o1 = {};
  float su0 = 0.0f, su1 = 0.0f, su2 = 0.0f, su3 = 0.0f;

  ASTAGE(0, 0);
  __syncthreads();
  const int NT = SEQ / 64;  // 32
#pragma unroll 2
  for (int it = 0; it < NT; ++it) {
    const int cur = it & 1;
    if (it + 1 < NT) ASTAGE(cur ^ 1, (it + 1) * 64);

    f32x16 s0 = {}, s1 = {};
    __builtin_amdgcn_s_setprio(1);
#pragma unroll
    for (int dc = 0; dc < 4; ++dc) {
      const int colb = dc * 16 + hi * 8;
      bf16x8 kf0 = *(const bf16x8*)&kl[cur][q32 * 64 + (colb ^ ksw)];
      bf16x8 kf1 = *(const bf16x8*)&kl[cur][(32 + q32) * 64 + (colb ^ ksw)];
      s0 = MFMA32(kf0, qf[dc], s0);
      s1 = MFMA32(kf1, qf[dc], s1);
    }
    __builtin_amdgcn_s_setprio(0);

#pragma unroll
    for (int r = 0; r < 16; r += 4) {
      s0[r + 0] = fexp2(s0[r + 0]); su0 += s0[r + 0];
      s0[r + 1] = fexp2(s0[r + 1]); su1 += s0[r + 1];
      s0[r + 2] = fexp2(s0[r + 2]); su2 += s0[r + 2];
      s0[r + 3] = fexp2(s0[r + 3]); su3 += s0[r + 3];
    }
#pragma unroll
    for (int r = 0; r < 16; r += 4) {
      s1[r + 0] = fexp2(s1[r + 0]); su0 += s1[r + 0];
      s1[r + 1] = fexp2(s1[r + 1]); su1 += s1[r + 1];
      s1[r + 2] = fexp2(s1[r + 2]); su2 += s1[r + 2];
      s1[r + 3] = fexp2(s1[r + 3]); su3 += s1[r + 3];
    }

    bf16x8 pav[4];
#pragma unroll
    for (int c = 0; c < 4; ++c) {
      const int b = 8 * (c & 1);
      unsigned int wA0, wA1, wB0, wB1;
      if (c < 2) {
        PACKBF(wA0, s0[b + 0], s0[b + 1]); PACKBF(wA1, s0[b + 2], s0[b + 3]);
        PACKBF(wB0, s0[b + 4], s0[b + 5]); PACKBF(wB1, s0[b + 6], s0[b + 7]);
      } else {
        PACKBF(wA0, s1[b + 0], s1[b + 1]); PACKBF(wA1, s1[b + 2], s1[b + 3]);
        PACKBF(wB0, s1[b + 4], s1[b + 5]); PACKBF(wB1, s1[b + 6], s1[b + 7]);
      }
      SWAP32(wA0, wB0);
      SWAP32(wA1, wB1);
      union { unsigned int w[4]; bf16x8 v; } u;
      u.w[0] = wA0; u.w[1] = wA1; u.w[2] = wB0; u.w[3] = wB1;
      pav[c] = u.v;
    }

    __builtin_amdgcn_s_setprio(1);
#pragma unroll
    for (int c = 0; c < 4; ++c) {
      const int colb = c * 16 + hi * 8;
      bf16x8 vf0 = *(const bf16x8*)&vt[cur][q32 * 64 + (colb ^ ksw)];
      bf16x8 vf1 = *(const bf16x8*)&vt[cur][(32 + q32) * 64 + (colb ^ ksw)];
      o0 = MFMA32(pav[c], vf0, o0);
      o1 = MFMA32(pav[c], vf1, o1);
    }
    __builtin_amdgcn_s_setprio(0);
    __syncthreads();
  }
#undef ASTAGE

  float lsum = (su0 + su1) + (su2 + su3);
  lsum += __shfl_xor(lsum, 32, 64);
  linv[wave][q32] = __builtin_amdgcn_rcpf(lsum);
  __syncthreads();

  const int b = bh / NH, h = bh % NH;
#pragma unroll
  for (int r = 0; r < 16; ++r) {
    const int qq = (r & 3) + 8 * (r >> 2) + 4 * hi;
    const float iv = linv[wave][qq];
    size_t base = ((size_t)(b * SEQ + qbase + qq)) * CD + h * DH;
    Ob[base + q32] = f2bf(o0[r] * iv);
    Ob[base + 32 + q32] = f2bf(o1[r] * iv);
  }
}

// ---------------- Proj GEMM: 128x128 tile, BK=64, swizzled LDS, fp32 out ----------------
__global__ __launch_bounds__(256) void proj_gemm(
    const unsigned short* __restrict__ Ab, const unsigned short* __restrict__ Wb,
    const float* __restrict__ bias, float* __restrict__ out) {
  __shared__ unsigned short Als[2][128 * 64];   // 32KB
  __shared__ unsigned short Bls[2][128 * 64];   // 32KB
  const int tid = threadIdx.x;
  const int wid = tid >> 6, lane = tid & 63;
  const int g = lane >> 4, cl = lane & 15;
  const int bm = blockIdx.x, bn = blockIdx.y;
  const int wr = (wid >> 1) * 64, wc = (wid & 1) * 64;

  f32x4 acc[4][4] = {};

  const int srow = tid >> 3;                      // 0..31
  const int scol = ((tid & 7) ^ (srow & 7)) * 8;
  const unsigned short* Abase = Ab + (size_t)(bm * 128 + srow) * CD + scol;
  const unsigned short* Bbase = Wb + (size_t)(bn * 128 + srow) * CD + scol;

#define PSTG(buf, kt)                                                         \
  do {                                                                        \
    gl2lds16(Abase + (size_t)0 * 32 * CD + (kt) * 64, &Als[buf][0 * 2048 + tid * 8]); \
    gl2lds16(Abase + (size_t)1 * 32 * CD + (kt) * 64, &Als[buf][1 * 2048 + tid * 8]); \
    gl2lds16(Abase + (size_t)2 * 32 * CD + (kt) * 64, &Als[buf][2 * 2048 + tid * 8]); \
    gl2lds16(Abase + (size_t)3 * 32 * CD + (kt) * 64, &Als[buf][3 * 2048 + tid * 8]); \
    gl2lds16(Bbase + (size_t)0 * 32 * CD + (kt) * 64, &Bls[buf][0 * 2048 + tid * 8]); \
    gl2lds16(Bbase + (size_t)1 * 32 * CD + (kt) * 64, &Bls[buf][1 * 2048 + tid * 8]); \
    gl2lds16(Bbase + (size_t)2 * 32 * CD + (kt) * 64, &Bls[buf][2 * 2048 + tid * 8]); \
    gl2lds16(Bbase + (size_t)3 * 32 * CD + (kt) * 64, &Bls[buf][3 * 2048 + tid * 8]); \
  } while (0)

  PSTG(0, 0);
  __syncthreads();
  const int NKT = CD / 64;  // 12
  for (int kt = 0; kt < NKT; ++kt) {
    const int cur = kt & 1;
    if (kt + 1 < NKT) PSTG(cur ^ 1, kt + 1);
    bf16x8 bfr[4][2];
#pragma unroll
    for (int j = 0; j < 4; ++j) {
      const int Bcol = wc + j * 16 + cl;
      const int sw = (Bcol & 7) << 3;
      bfr[j][0] = *(const bf16x8*)&Bls[cur][Bcol * 64 + ((g * 8) ^ sw)];
      bfr[j][1] = *(const bf16x8*)&Bls[cur][Bcol * 64 + ((32 + g * 8) ^ sw)];
    }
    __builtin_amdgcn_s_setprio(1);
#pragma unroll
    for (int i = 0; i < 4; ++i) {
      const int Arow = wr + i * 16 + cl;
      const int sw = (Arow & 7) << 3;
      bf16x8 a0 = *(const bf16x8*)&Als[cur][Arow * 64 + ((g * 8) ^ sw)];
      bf16x8 a1 = *(const bf16x8*)&Als[cur][Arow * 64 + ((32 + g * 8) ^ sw)];
#pragma unroll
      for (int j = 0; j < 4; ++j) {
        acc[i][j] = MFMA(a0, bfr[j][0], acc[i][j]);
        acc[i][j] = MFMA(a1, bfr[j][1], acc[i][j]);
      }
    }
    __builtin_amdgcn_s_setprio(0);
    __syncthreads();
  }
#undef PSTG

  const int j0 = bn * 128 + wc;
  float pb4[4];
#pragma unroll
  for (int j = 0; j < 4; ++j) pb4[j] = bias[j0 + j * 16 + cl];
#pragma unroll
  for (int i = 0; i < 4; ++i) {
#pragma unroll
    for (int r = 0; r < 4; ++r) {
      const int m = bm * 128 + wr + i * 16 + g * 4 + r;
      float* orow = out + (size_t)m * CD + j0;
#pragma unroll
      for (int j = 0; j < 4; ++j) orow[j * 16 + cl] = acc[i][j][r] + pb4[j];
    }
  }
}

extern "C" void kernel_launch(void* const* d_in, const int* in_sizes, int n_in,
                              void* d_out, int out_size, void* d_ws, size_t ws_size,
                              hipStream_t stream) {
  const float* x = (const float*)d_in[0];
  const float* qkv_w = (const float*)d_in[1];
  const float* qkv_b = (const float*)d_in[2];
  const float* proj_w = (const float*)d_in[3];
  const float* proj_b = (const float*)d_in[4];
  const float* q_gamma = (const float*)d_in[5];
  const float* q_beta = (const float*)d_in[6];
  const float* k_gamma = (const float*)d_in[7];
  const float* k_beta = (const float*)d_in[8];
  float* out = (float*)d_out;

  char* w = (char*)d_ws;
  unsigned short* Xb = (unsigned short*)w; w += (size_t)MROWS * CD * 2;
  unsigned short* Wq = (unsigned short*)w; w += (size_t)NQKV * CD * 2;
  unsigned short* Wp = (unsigned short*)w; w += (size_t)CD * CD * 2;
  unsigned short* Qo = (unsigned short*)w; w += (size_t)BB * NH * SEQ * DH * 2;
  unsigned short* Ko = (unsigned short*)w; w += (size_t)BB * NH * SEQ * DH * 2;
  unsigned short* Vt = (unsigned short*)w; w += (size_t)BB * NH * SEQ * DH * 2;  // [b,h,d,n]
  unsigned short* Ob = (unsigned short*)w; w += (size_t)MROWS * CD * 2;

  cvt_all<<<(CN3 + 255) / 256, 256, 0, stream>>>(x, qkv_w, proj_w, Xb, Wq, Wp);

  qkv_gemm<<<(MROWS / 128) * (NQKV / 128), 256, 0, stream>>>(
      Xb, Wq, qkv_b, q_gamma, q_beta, k_gamma, k_beta, Qo, Ko, Vt);

  attn_fwd<<<SEQ / 128 * BB * NH, 256, 0, stream>>>(Qo, Ko, Vt, Ob);

  proj_gemm<<<dim3(MROWS / 128, CD / 128), 256, 0, stream>>>(Ob, Wp, proj_b, out);
}